// Round 10
// baseline (197.665 us; speedup 1.0000x reference)
//
#include <hip/hip_runtime.h>
#include <math.h>

#define SS 4096
#define DD 512
#define HH 8
#define QKSCALE 0.1803368801111137f   // 0.125 * log2(e): folded into Wq; softmax in exp2 domain

typedef __attribute__((ext_vector_type(8))) short bf16x8;    // 8 bf16 = 4 VGPRs
typedef __attribute__((ext_vector_type(4))) float f32x4;
typedef __attribute__((ext_vector_type(16))) float f32x16;
typedef __attribute__((ext_vector_type(4))) unsigned int u32x4;

// async global->LDS, 16B per lane; LDS dest = wave-uniform base + lane*16
__device__ __forceinline__ void gl2lds16(const void* g, void* l) {
    __builtin_amdgcn_global_load_lds(
        (const __attribute__((address_space(1))) unsigned int*)(uintptr_t)g,
        (__attribute__((address_space(3))) unsigned int*)(uintptr_t)l,
        16, 0, 0);
}

__device__ __forceinline__ unsigned short f2bf(float f) {   // RNE fp32->bf16
    unsigned u = __float_as_uint(f);
    u += 0x7FFF + ((u >> 16) & 1);
    return (unsigned short)(u >> 16);
}

// pack two fp32 -> (bf16(hi)<<16)|bf16(lo), near-RNE (+0x8000)
__device__ __forceinline__ unsigned pk_bf(float lo, float hi) {
    unsigned ul = __float_as_uint(lo) + 0x8000u;
    unsigned uh = __float_as_uint(hi) + 0x8000u;
    return __builtin_amdgcn_perm(uh, ul, 0x07060302u);
}

// unpack (bf16 pair packed in unsigned) -> two fp32
__device__ __forceinline__ float2 upk_bf(unsigned u) {
    float2 r;
    r.x = __uint_as_float(u << 16);
    r.y = __uint_as_float(u & 0xFFFF0000u);
    return r;
}

// ---------------------------------------------------------------------------
// prep: blocks 0..4095 cast x (fp32 [8192][512]) -> bf16;
//       blocks 4096..4351 cast+transpose weights W[k][n] fp32 -> Wt[z][n][k]
//       bf16 (z==0 Wq pre-scaled by QKSCALE).
// ---------------------------------------------------------------------------
__global__ __launch_bounds__(256) void prep(const float* __restrict__ x,
                                            const float* __restrict__ Wq,
                                            const float* __restrict__ Wk,
                                            const float* __restrict__ Wv,
                                            const float* __restrict__ Wo,
                                            unsigned short* __restrict__ xb,
                                            unsigned short* __restrict__ Wt) {
    __shared__ unsigned short T[64 * 80];
    const int bx = blockIdx.x;
    const int t = threadIdx.x;
    if (bx < 4096) {
        int i = (bx * 256 + t) * 4;
        float4 v = *(const float4*)&x[i];
        ushort4 o;
        o.x = f2bf(v.x); o.y = f2bf(v.y); o.z = f2bf(v.z); o.w = f2bf(v.w);
        *(ushort4*)&xb[i] = o;
        return;
    }
    const int idx = bx - 4096;               // 0..255
    const int z = idx >> 6;
    const int k0 = ((idx >> 3) & 7) * 64, n0 = (idx & 7) * 64;
    const float* W = z == 0 ? Wq : z == 1 ? Wk : z == 2 ? Wv : Wo;
    const float scale = (z == 0) ? QKSCALE : 1.0f;
    unsigned short* dst = Wt + (size_t)z * DD * DD;
    #pragma unroll
    for (int it = 0; it < 4; it++) {
        int i = t + it * 256;
        int kr = i >> 4, nc = (i & 15) * 4;
        float4 v = *(const float4*)&W[(size_t)(k0 + kr) * DD + n0 + nc];
        T[(nc + 0) * 80 + kr] = f2bf(v.x * scale);
        T[(nc + 1) * 80 + kr] = f2bf(v.y * scale);
        T[(nc + 2) * 80 + kr] = f2bf(v.z * scale);
        T[(nc + 3) * 80 + kr] = f2bf(v.w * scale);
    }
    __syncthreads();
    #pragma unroll
    for (int it = 0; it < 2; it++) {
        int i = t + it * 256;
        int nr = i >> 3, kc = (i & 7) * 8;
        bf16x8 v = *(const bf16x8*)&T[nr * 80 + kc];
        *(bf16x8*)&dst[(size_t)(n0 + nr) * DD + k0 + kc] = v;
    }
}

// ---------------------------------------------------------------------------
// transpose V: [bh][s][64] bf16 -> Vt [bh][64][4096] bf16   (R7-proven)
// ---------------------------------------------------------------------------
__global__ __launch_bounds__(256) void v_transpose_kernel(const unsigned short* __restrict__ V,
                                                          unsigned short* __restrict__ Vt) {
    const int s0 = blockIdx.x * 64;
    const int bh = blockIdx.y;
    __shared__ unsigned short T[64 * 80];
    const int t = threadIdx.x;
    const unsigned short* Vg = V + (size_t)bh * SS * 64;
    #pragma unroll
    for (int it = 0; it < 2; it++) {
        int i = t + it * 256;
        int sr = i >> 3, dc = (i & 7) * 8;
        bf16x8 v = *(const bf16x8*)&Vg[(size_t)(s0 + sr) * 64 + dc];
        #pragma unroll
        for (int j = 0; j < 8; j++) T[(dc + j) * 80 + sr] = (unsigned short)v[j];
    }
    __syncthreads();
    unsigned short* Vtg = Vt + (size_t)bh * 64 * SS;
    #pragma unroll
    for (int it = 0; it < 2; it++) {
        int i = t + it * 256;
        int dr = i >> 3, sc = (i & 7) * 8;
        bf16x8 v = *(const bf16x8*)&T[dr * 80 + sc];
        *(bf16x8*)&Vtg[(size_t)dr * SS + s0 + sc] = v;
    }
}

// ---------------------------------------------------------------------------
// bf16 MFMA GEMM, 128x128 tile, BK=64, 256 thr = 4 waves (2x2). R7-proven
// body. R10: grid roles SWAPPED — blockIdx.x = n-tile (small), blockIdx.y =
// m-tile — so consecutive blocks share the A-tile (128 KB, L2-hot) and the
// whole B (<=1.5 MB) stays L2-resident: A is fetched from HBM once instead
// of grid.x times.
// MODE 0: A=x_bf16 [8192][512], B=Wt rows (z fused in grid.x),
//         out = Q/K/V bf16 head-split [bh][s][64]
// MODE 1: A=Oh head-split [bh][s][64] (k0 selects head), B=Wt[3],
//         out fp32 [8192][512]
// ---------------------------------------------------------------------------
template <int MODE>
__global__ __launch_bounds__(256) void gemm128(const unsigned short* __restrict__ A,
                                               const unsigned short* __restrict__ WtAll,
                                               const float* __restrict__ b0,
                                               const float* __restrict__ b1,
                                               const float* __restrict__ b2,
                                               void* __restrict__ out) {
    const int tid = threadIdx.x;
    const int wave = tid >> 6, lane = tid & 63;
    const int quad = lane >> 4, l16 = lane & 15;
    const int wm = wave >> 1, wn = wave & 1;
    const int bm0 = blockIdx.y * 128;            // R10 swap: m from y
    const int n_tot = blockIdx.x * 128;          // R10 swap: n from x
    const int z = (MODE == 0) ? (n_tot >> 9) : 3;
    const int bn0 = (MODE == 0) ? (n_tot & 511) : n_tot;

    const unsigned short* Bt = (MODE == 0) ? (WtAll + (size_t)n_tot * DD)
                                           : (WtAll + (size_t)3 * DD * DD + (size_t)bn0 * DD);

    __shared__ unsigned short As[128 * 64];
    __shared__ unsigned short Bs[128 * 64];

    f32x4 acc[4][4] = {};

    const int lr = lane >> 3;
    const int cpp = lane & 7;

    for (int k0 = 0; k0 < DD; k0 += 64) {
        __syncthreads();
        #pragma unroll
        for (int t = 0; t < 4; t++) {
            int r0 = wave * 32 + t * 8;
            int m = r0 + lr;
            if (MODE == 0) {
                gl2lds16(&A[(size_t)(bm0 + m) * DD + k0 + ((cpp ^ (m & 7)) << 3)], &As[r0 * 64]);
            } else {
                int gm = bm0 + m;
                gl2lds16(&A[((size_t)((gm >> 12) * HH + (k0 >> 6)) * SS + (gm & (SS - 1))) * 64
                            + ((cpp ^ (m & 7)) << 3)], &As[r0 * 64]);
            }
            gl2lds16(&Bt[(size_t)m * DD + k0 + ((cpp ^ (m & 7)) << 3)], &Bs[r0 * 64]);
        }
        __syncthreads();
        #pragma unroll
        for (int kk = 0; kk < 2; kk++) {
            bf16x8 af[4], bfr[4];
            #pragma unroll
            for (int mf = 0; mf < 4; mf++) {
                int m = wm * 64 + mf * 16 + l16;
                af[mf] = *(const bf16x8*)&As[m * 64 + (((kk * 4 + quad) ^ (m & 7)) << 3)];
            }
            #pragma unroll
            for (int nf = 0; nf < 4; nf++) {
                int n = wn * 64 + nf * 16 + l16;
                bfr[nf] = *(const bf16x8*)&Bs[n * 64 + (((kk * 4 + quad) ^ (n & 7)) << 3)];
            }
            #pragma unroll
            for (int mf = 0; mf < 4; mf++)
                #pragma unroll
                for (int nf = 0; nf < 4; nf++)
                    acc[mf][nf] = __builtin_amdgcn_mfma_f32_16x16x32_bf16(af[mf], bfr[nf], acc[mf][nf], 0, 0, 0);
        }
    }

    const float bscale = (MODE == 0 && z == 0) ? QKSCALE : 1.0f;
    const float* bias = (MODE == 0) ? (z == 0 ? b0 : z == 1 ? b1 : b2) : b0;
    #pragma unroll
    for (int nf = 0; nf < 4; nf++) {
        int n = bn0 + wn * 64 + nf * 16 + l16;
        float bv = bias[n] * bscale;
        #pragma unroll
        for (int mf = 0; mf < 4; mf++) {
            #pragma unroll
            for (int r = 0; r < 4; r++) {
                int m = bm0 + wm * 64 + mf * 16 + quad * 4 + r;
                float val = acc[mf][nf][r] + bv;
                if (MODE == 0) {
                    int b = m >> 12, s = m & (SS - 1);
                    int h = n >> 6, d = n & 63;
                    unsigned short* dst = (unsigned short*)out + (size_t)z * 4194304;
                    dst[(((size_t)(b * HH + h)) * SS + s) * 64 + d] = f2bf(val);
                } else {
                    ((float*)out)[(size_t)m * DD + n] = val;
                }
            }
        }
    }
}

// ---------------------------------------------------------------------------
// Chunked MFMA flash attention (causal), 32x32x16, max-free exp2 softmax.
// Partials combine by pure addition (no max tracking). 90 near-uniform chunk
// ids (<=14 k-tiles each). R10: grid = (16 bh, 90 chunks) so block linear id
// = bh + 16*chunk -> id%8 == bh%8: with the %8 XCD round-robin heuristic all
// blocks of one bh land on one XCD, pinning that bh's 4 MB K+Vt working set
// in its L2. bf16 O-partials [id][bh][128][64] in dead ws regions.
// ---------------------------------------------------------------------------
__global__ __launch_bounds__(256, 3) void attn_chunk(const unsigned short* __restrict__ Q,
                                                     const unsigned short* __restrict__ K,
                                                     const unsigned short* __restrict__ Vt,
                                                     unsigned short* __restrict__ P0,
                                                     unsigned short* __restrict__ P1,
                                                     unsigned short* __restrict__ P2,
                                                     float* __restrict__ Lpart) {
    const int id = 89 - (int)blockIdx.y;   // big chunks (high qt) first
    int qt, c;
    if (id < 7)       { qt = id;                 c = 0; }
    else if (id < 21) { int t = id - 7;  qt = 7 + t / 2;  c = t % 2; }
    else if (id < 42) { int t = id - 21; qt = 14 + t / 3; c = t % 3; }
    else if (id < 70) { int t = id - 42; qt = 21 + t / 4; c = t % 4; }
    else              { int t = id - 70; qt = 28 + t / 5; c = t % 5; }
    const int nc = (qt < 7) ? 1 : (qt < 14) ? 2 : (qt < 21) ? 3 : (qt < 28) ? 4 : 5;
    const int nk = 2 * qt + 2;
    const int bsz = nk / nc, rem = nk % nc;
    const int ks = c * bsz + (c < rem ? c : rem);
    const int nit = bsz + (c < rem ? 1 : 0);

    const int bh = blockIdx.x;             // R10: bh from x (XCD pinning)
    const int tid = threadIdx.x;
    const int wave = tid >> 6, lane = tid & 63;
    const int h = lane >> 5, l31 = lane & 31;
    const int lr = lane >> 3, cpp = lane & 7;

    __shared__ unsigned short sb[16384];   // 32 KB: K dbuf + V dbuf; reused as fp32 [128][64]
    unsigned short* Ksb0 = sb;
    unsigned short* Ksb1 = sb + 4096;
    unsigned short* Vsb0 = sb + 8192;
    unsigned short* Vsb1 = sb + 12288;

    const unsigned short* Qg = Q + (size_t)bh * SS * 64;
    const unsigned short* Kg = K + (size_t)bh * SS * 64;
    const unsigned short* Vtg = Vt + (size_t)bh * 64 * SS;

    const int q0w = qt * 128 + wave * 32;
    const int qrow = q0w + l31;
    const int qmaxw = q0w + 31;

    // Q B-frags: B[k = cc*16 + h*8 + j][n = q]
    bf16x8 qf[4];
    #pragma unroll
    for (int cc = 0; cc < 4; cc++)
        qf[cc] = *(const bf16x8*)&Qg[(size_t)qrow * 64 + cc * 16 + h * 8];

    bf16x8 onesA;
    #pragma unroll
    for (int j = 0; j < 8; j++) onesA[j] = (short)0x3F80;

    f32x16 fz;
    #pragma unroll
    for (int i = 0; i < 16; i++) fz[i] = 0.f;

    f32x16 oacc[2]; oacc[0] = fz; oacc[1] = fz;   // O^T[d = 32*dh + rmap][q]
    f32x16 lacc = fz;                             // l[q] replicated over rows

    // ---- stage k-tile ks into buf 0 ----
    #pragma unroll
    for (int t = 0; t < 2; t++) {
        int r0 = wave * 16 + t * 8;
        int m = r0 + lr;
        gl2lds16(&Kg[(size_t)(ks * 64 + m) * 64 + ((cpp ^ (m & 7)) << 3)], &Ksb0[r0 * 64]);
        gl2lds16(&Vtg[(size_t)m * SS + ks * 64 + ((cpp ^ (m & 7)) << 3)], &Vsb0[r0 * 64]);
    }

    for (int it = 0; it < nit; it++) {
        const int kt = ks + it;
        __syncthreads();   // stage(it) complete; all reads of the other buf done
        if (it + 1 < nit) {
            unsigned short* Kn = ((it + 1) & 1) ? Ksb1 : Ksb0;
            unsigned short* Vn = ((it + 1) & 1) ? Vsb1 : Vsb0;
            #pragma unroll
            for (int t = 0; t < 2; t++) {
                int r0 = wave * 16 + t * 8;
                int m = r0 + lr;
                gl2lds16(&Kg[(size_t)((kt + 1) * 64 + m) * 64 + ((cpp ^ (m & 7)) << 3)], &Kn[r0 * 64]);
                gl2lds16(&Vtg[(size_t)m * SS + (kt + 1) * 64 + ((cpp ^ (m & 7)) << 3)], &Vn[r0 * 64]);
            }
        }
        if (kt * 64 > qmaxw) continue;   // fully-masked for this wave (still barriers)

        const unsigned short* Kb = (it & 1) ? Ksb1 : Ksb0;
        const unsigned short* Vb = (it & 1) ? Vsb1 : Vsb0;

        // ---- S^T = K Q^T ----
        f32x16 sc0 = fz, sc1 = fz;
        #pragma unroll
        for (int cc = 0; cc < 4; cc++) {
            bf16x8 k0 = *(const bf16x8*)&Kb[(0 * 32 + l31) * 64 + (((2 * cc + h) ^ (l31 & 7)) << 3)];
            bf16x8 k1 = *(const bf16x8*)&Kb[(1 * 32 + l31) * 64 + (((2 * cc + h) ^ (l31 & 7)) << 3)];
            sc0 = __builtin_amdgcn_mfma_f32_32x32x16_bf16(k0, qf[cc], sc0, 0, 0, 0);
            sc1 = __builtin_amdgcn_mfma_f32_32x32x16_bf16(k1, qf[cc], sc1, 0, 0, 0);
        }

        // ---- diagonal mask: key > q -> -inf (exp2 -> 0) ----
        if (kt * 64 + 63 > q0w) {   // guard vs MIN q-row of the wave
            #pragma unroll
            for (int r = 0; r < 16; r++) {
                int rm = (r & 3) + 8 * (r >> 2) + 4 * h;
                if (kt * 64 + rm > qrow) sc0[r] = -INFINITY;
                if (kt * 64 + 32 + rm > qrow) sc1[r] = -INFINITY;
            }
        }

        // ---- p = exp2(s) (raw v_exp_f32), packed bf16 pairs ----
        unsigned pk[2][4][2];
        #pragma unroll
        for (int bq = 0; bq < 4; bq++)
            #pragma unroll
            for (int pr = 0; pr < 2; pr++) {
                int r = 4 * bq + 2 * pr;
                pk[0][bq][pr] = pk_bf(__builtin_amdgcn_exp2f(sc0[r]), __builtin_amdgcn_exp2f(sc0[r + 1]));
                pk[1][bq][pr] = pk_bf(__builtin_amdgcn_exp2f(sc1[r]), __builtin_amdgcn_exp2f(sc1[r + 1]));
            }

        // ---- exchange to P^T B-frags (lane<->lane^32 only) + PV + l ----
        #pragma unroll
        for (int jt = 0; jt < 4; jt++) {
            const int kh = jt >> 1, be = 2 * (jt & 1);
            unsigned own0 = h ? pk[kh][be + 1][0] : pk[kh][be][0];
            unsigned own1 = h ? pk[kh][be + 1][1] : pk[kh][be][1];
            unsigned snd0 = h ? pk[kh][be][0] : pk[kh][be + 1][0];
            unsigned snd1 = h ? pk[kh][be][1] : pk[kh][be + 1][1];
            unsigned rc0 = (unsigned)__shfl_xor((int)snd0, 32);
            unsigned rc1 = (unsigned)__shfl_xor((int)snd1, 32);
            u32x4 pw;
            pw[0] = h ? rc0 : own0;
            pw[1] = h ? rc1 : own1;
            pw[2] = h ? own0 : rc0;
            pw[3] = h ? own1 : rc1;
            bf16x8 pf = __builtin_bit_cast(bf16x8, pw);
            #pragma unroll
            for (int dh = 0; dh < 2; dh++) {
                bf16x8 vfr = *(const bf16x8*)&Vb[(dh * 32 + l31) * 64 + (((2 * jt + h) ^ (l31 & 7)) << 3)];
                oacc[dh] = __builtin_amdgcn_mfma_f32_32x32x16_bf16(vfr, pf, oacc[dh], 0, 0, 0);
            }
            lacc = __builtin_amdgcn_mfma_f32_32x32x16_bf16(onesA, pf, lacc, 0, 0, 0);
        }
    }

    // ---- epilogue: O^T regs -> swizzled LDS [q][d] fp32 -> bf16 partial ----
    __syncthreads();
    float* ob = (float*)sb;
    const int q = wave * 32 + l31;
    #pragma unroll
    for (int dh = 0; dh < 2; dh++)
        #pragma unroll
        for (int bq = 0; bq < 4; bq++) {
            int d4 = 2 * bq + h + 8 * dh;
            float4 v4;
            v4.x = oacc[dh][4 * bq + 0];
            v4.y = oacc[dh][4 * bq + 1];
            v4.z = oacc[dh][4 * bq + 2];
            v4.w = oacc[dh][4 * bq + 3];
            *(float4*)&ob[q * 64 + ((d4 ^ (l31 & 15)) << 2)] = v4;
        }
    if (h == 0) Lpart[((size_t)id * 16 + bh) * 128 + q] = lacc[0];
    __syncthreads();
    unsigned short* Og = (id < 32 ? P0 + (size_t)id * 131072
                        : id < 64 ? P1 + (size_t)(id - 32) * 131072
                                  : P2 + (size_t)(id - 64) * 131072) + (size_t)bh * 8192;
    #pragma unroll
    for (int it = 0; it < 4; it++) {
        int flat = it * 256 + tid;           // 0..1023
        int qq = flat >> 3, d8 = flat & 7;
        float4 a = *(const float4*)&ob[qq * 64 + (((d8 * 2) ^ (qq & 15)) << 2)];
        float4 bb = *(const float4*)&ob[qq * 64 + (((d8 * 2 + 1) ^ (qq & 15)) << 2)];
        u32x4 o;
        o[0] = pk_bf(a.x, a.y);
        o[1] = pk_bf(a.z, a.w);
        o[2] = pk_bf(bb.x, bb.y);
        o[3] = pk_bf(bb.z, bb.w);
        *(u32x4*)&Og[qq * 64 + d8 * 8] = o;
    }
}

// ---------------------------------------------------------------------------
// reduce partials: Oh[bh][s][d] = bf16( sum_c Opart / sum_c Lpart )
// ---------------------------------------------------------------------------
__global__ __launch_bounds__(256) void reduce_o(const unsigned short* __restrict__ P0,
                                                const unsigned short* __restrict__ P1,
                                                const unsigned short* __restrict__ P2,
                                                const float* __restrict__ Lpart,
                                                unsigned short* __restrict__ Oh) {
    const int qt = blockIdx.x, bh = blockIdx.y;
    int nc, qs;
    if (qt < 7)       { nc = 1; qs = qt; }
    else if (qt < 14) { nc = 2; qs = 7 + 2 * (qt - 7); }
    else if (qt < 21) { nc = 3; qs = 21 + 3 * (qt - 14); }
    else if (qt < 28) { nc = 4; qs = 42 + 4 * (qt - 21); }
    else              { nc = 5; qs = 70 + 5 * (qt - 28); }
    const int t = threadIdx.x;
    #pragma unroll
    for (int it = 0; it < 4; it++) {
        int flat = it * 256 + t;
        int q = flat >> 3, d8 = flat & 7;
        float s[8] = {};
        float l = 0.f;
        for (int ic = 0; ic < nc; ic++) {
            int idd = qs + ic;
            const unsigned short* Og = (idd < 32 ? P0 + (size_t)idd * 131072
                                      : idd < 64 ? P1 + (size_t)(idd - 32) * 131072
                                                 : P2 + (size_t)(idd - 64) * 131072) + (size_t)bh * 8192;
            u32x4 u = *(const u32x4*)&Og[q * 64 + d8 * 8];
            #pragma unroll
            for (int j = 0; j < 4; j++) {
                float2 f = upk_bf(u[j]);
                s[2 * j + 0] += f.x;
                s[2 * j + 1] += f.y;
            }
            l += Lpart[((size_t)idd * 16 + bh) * 128 + q];
        }
        float inv = 1.f / l;
        u32x4 o;
        #pragma unroll
        for (int j = 0; j < 4; j++)
            o[j] = pk_bf(s[2 * j] * inv, s[2 * j + 1] * inv);
        *(u32x4*)&Oh[(((size_t)bh * SS) + qt * 128 + q) * 64 + d8 * 8] = o;
    }
}

// ---------------------------------------------------------------------------
extern "C" void kernel_launch(void* const* d_in, const int* in_sizes, int n_in,
                              void* d_out, int out_size, void* d_ws, size_t ws_size,
                              hipStream_t stream) {
    const float* x  = (const float*)d_in[0];
    const float* Wq = (const float*)d_in[1];
    const float* bq = (const float*)d_in[2];
    const float* Wk = (const float*)d_in[3];
    const float* bk = (const float*)d_in[4];
    const float* Wv = (const float*)d_in[5];
    const float* bv = (const float*)d_in[6];
    const float* Wo = (const float*)d_in[7];
    const float* bo = (const float*)d_in[8];
    float* out = (float*)d_out;

    // ws layout (ushort elements), total 49.2 MB (< 52.4 MB proven safe):
    //   xb   @ 0         (4M)  dead after gemm0       -> partials ids 0..31
    //   Wt   @ 4194304   (1M)
    //   Q    @ 5242880   (4M)  dead after attn        -> Oh
    //   K    @ 9437184   (4M)
    //   V    @ 13631488  (4M)  dead after v_transpose -> partials ids 32..63
    //   Vt   @ 17825792  (4M)
    //   tail @ byte 44040192: partials ids 64..89 (6.82 MB), Lpart fp32 (737 KB)
    unsigned short* xb  = (unsigned short*)d_ws;
    unsigned short* Wt  = xb + 4194304;
    unsigned short* QKV = Wt + 1048576;
    unsigned short* Vw  = QKV + 2 * (size_t)4194304;
    unsigned short* Vtw = QKV + 3 * (size_t)4194304;
    unsigned short* P0  = xb;
    unsigned short* P1  = Vw;
    unsigned short* P2  = (unsigned short*)((char*)d_ws + 44040192);
    float* Lpart = (float*)((char*)d_ws + 44040192 + 6815744);
    unsigned short* Oh  = QKV;

    prep<<<4352, 256, 0, stream>>>(x, Wq, Wk, Wv, Wo, xb, Wt);
    gemm128<0><<<dim3(12, 64), 256, 0, stream>>>(xb, Wt, bq, bk, bv, QKV);
    v_transpose_kernel<<<dim3(64, 16), 256, 0, stream>>>(Vw, Vtw);
    attn_chunk<<<dim3(16, 90), 256, 0, stream>>>(QKV, QKV + 4194304, Vtw, P0, P1, P2, Lpart);
    reduce_o<<<dim3(32, 16), 256, 0, stream>>>(P0, P1, P2, Lpart, Oh);
    gemm128<1><<<dim3(4, 64), 256, 0, stream>>>(Oh, Wt, bo, nullptr, nullptr, out);
}